// Round 1
// baseline (277.421 us; speedup 1.0000x reference)
//
#include <hip/hip_runtime.h>

#define D_FEAT 32

__global__ void deg_kernel(const int* __restrict__ dst, float* __restrict__ deg, int E) {
    int i = blockIdx.x * blockDim.x + threadIdx.x;
    int stride = gridDim.x * blockDim.x;
    for (; i < E; i += stride) {
        atomicAdd(&deg[dst[i]], 1.0f);
    }
}

__global__ void inv_kernel(const float* __restrict__ deg, float* __restrict__ inv, int N) {
    int i = blockIdx.x * blockDim.x + threadIdx.x;
    if (i < N) inv[i] = rsqrtf(1.0f + deg[i]);
}

// 32 threads per edge: thread (e, d) adds inv[src[e]] * feat[src[e]][d] into out[dst[e]][d].
__global__ void scatter_kernel(const float* __restrict__ feat,
                               const int* __restrict__ src,
                               const int* __restrict__ dst,
                               const float* __restrict__ inv,
                               float* __restrict__ out, int E) {
    long long tid = (long long)blockIdx.x * blockDim.x + threadIdx.x;
    int e = (int)(tid >> 5);
    int d = (int)(tid & 31);
    if (e >= E) return;
    int s = src[e];
    int t = dst[e];
    float v = inv[s] * feat[s * D_FEAT + d];
    atomicAdd(&out[t * D_FEAT + d], v);
}

// out[i][d] = inv[i] * (acc[i][d] + inv[i] * feat[i][d])   (self-loop folded in)
__global__ void finalize_kernel(const float* __restrict__ feat,
                                const float* __restrict__ inv,
                                float* __restrict__ out, int ND) {
    int tid = blockIdx.x * blockDim.x + threadIdx.x;
    if (tid >= ND) return;
    int i = tid >> 5;  // D_FEAT == 32
    float iv = inv[i];
    out[tid] = iv * (out[tid] + iv * feat[tid]);
}

extern "C" void kernel_launch(void* const* d_in, const int* in_sizes, int n_in,
                              void* d_out, int out_size, void* d_ws, size_t ws_size,
                              hipStream_t stream) {
    const float* feat = (const float*)d_in[0];
    const int* esrc = (const int*)d_in[1];
    const int* edst = (const int*)d_in[2];
    float* out = (float*)d_out;

    const int N = in_sizes[0] / D_FEAT;   // 100000
    const int E = in_sizes[1];            // 1600000
    const int ND = N * D_FEAT;

    float* deg = (float*)d_ws;            // N floats
    float* inv = deg + N;                 // N floats

    // zero deg accumulator and output accumulator (harness poisons them to 0xAA)
    hipMemsetAsync(deg, 0, (size_t)N * sizeof(float), stream);
    hipMemsetAsync(out, 0, (size_t)ND * sizeof(float), stream);

    {
        int block = 256;
        int grid = (E + block - 1) / block;
        if (grid > 2048) grid = 2048;  // grid-stride
        deg_kernel<<<grid, block, 0, stream>>>(edst, deg, E);
    }
    {
        int block = 256;
        int grid = (N + block - 1) / block;
        inv_kernel<<<grid, block, 0, stream>>>(deg, inv, N);
    }
    {
        long long total = (long long)E * D_FEAT;
        int block = 256;
        long long grid = (total + block - 1) / block;
        scatter_kernel<<<(int)grid, block, 0, stream>>>(feat, esrc, edst, inv, out, E);
    }
    {
        int block = 256;
        int grid = (ND + block - 1) / block;
        finalize_kernel<<<grid, block, 0, stream>>>(feat, inv, out, ND);
    }
}